// Round 1
// baseline (1181.227 us; speedup 1.0000x reference)
//
#include <hip/hip_runtime.h>
#include <cstdint>
#include <cstddef>

// Problem constants
#define BB   128
#define DD   768
#define LL   131072
#define NBL  512
#define WDC  1e-4f

typedef __attribute__((ext_vector_type(8))) short bf16x8;
typedef __attribute__((ext_vector_type(4))) float f32x4;

__device__ __forceinline__ unsigned short f2bf(float f) {
  union { float f; unsigned u; } v; v.f = f;
  unsigned r = v.u + 0x7fffu + ((v.u >> 16) & 1u);   // RNE
  return (unsigned short)(r >> 16);
}
__device__ __forceinline__ float bf2f(unsigned short h) {
  union { unsigned u; float f; } v; v.u = ((unsigned)h) << 16;
  return v.f;
}

// ---------------------------------------------------------------------------
// K0: E fp32 -> bf16 in two layouts ([b][d] and [d][b]); zero grad region.
// grid 384 x 256 covers 98304 elements.
// ---------------------------------------------------------------------------
__global__ __launch_bounds__(256) void k0_prep(const float* __restrict__ E,
                                               float* __restrict__ grad,
                                               unsigned short* __restrict__ Ebd,
                                               unsigned short* __restrict__ Edb) {
  int i = blockIdx.x * 256 + threadIdx.x;      // < 98304
  float v = E[i];
  unsigned short b = f2bf(v);
  Ebd[i] = b;
  int bb = i / DD, d = i - bb * DD;
  Edb[d * BB + bb] = b;                        // transposed layout
  grad[i] = 0.0f;                              // init grad accumulator (d_out)
}

// ---------------------------------------------------------------------------
// K1: P = sigmoid(E @ W^T) with label scatter (set semantics).
// grid 1024 blocks, each computes a 128(b) x 128(l) tile, K = 768.
// Writes P bf16 in both [b][l] (Pbl) and [l][b] (Plb) layouts.
// ---------------------------------------------------------------------------
__global__ __launch_bounds__(256) void k1_logits(const float* __restrict__ W,
                                                 const unsigned short* __restrict__ Ebd,
                                                 const int* __restrict__ labels_raw,
                                                 unsigned short* __restrict__ Pbl,
                                                 unsigned short* __restrict__ Plb) {
  __shared__ __align__(16) char ldsbuf[36864];          // Ea+Wb staging, reused as P tile
  __shared__ int rawbuf[1024];
  __shared__ int lrows[NBL], lcols[NBL];
  __shared__ int modeSh;

  unsigned short* Ea = (unsigned short*)ldsbuf;           // [128][72] bf16
  unsigned short* Wb = (unsigned short*)(ldsbuf + 18432); // [128][72] bf16

  const int tid  = threadIdx.x;
  const int lane = tid & 63;
  const int wave = tid >> 6;
  const int wm = wave & 1, wn = wave >> 1;
  const int q = lane >> 4, c = lane & 15;
  const int l0 = blockIdx.x * 128;

  // ---- label decode (handles labels delivered as int32 pairs OR int64 pairs)
  #pragma unroll
  for (int p = 0; p < 4; ++p) rawbuf[tid + p * 256] = labels_raw[tid + p * 256];
  if (tid == 0) modeSh = 0;
  __syncthreads();
  int o = 0;
  #pragma unroll
  for (int p = 0; p < 2; ++p) o |= rawbuf[(tid + p * 256) * 2 + 1];
  if (o) atomicOr(&modeSh, 1);
  __syncthreads();
  const int is32 = modeSh;   // 1 => int32 pairs; 0 => int64 pairs (high words all zero)
  #pragma unroll
  for (int p = 0; p < 2; ++p) {
    int i = tid + p * 256;
    if (is32) { lrows[i] = rawbuf[2 * i];      lcols[i] = rawbuf[2 * i + 1]; }
    else      { lrows[i] = labels_raw[4 * i];  lcols[i] = labels_raw[4 * i + 2]; }
  }
  __syncthreads();

  f32x4 acc[4][4];
  #pragma unroll
  for (int i = 0; i < 4; ++i)
    #pragma unroll
    for (int j = 0; j < 4; ++j) acc[i][j] = 0.0f;

  for (int k0 = 0; k0 < DD; k0 += 64) {
    // stage E tile [128][64] bf16 from ws (16B chunks)
    #pragma unroll
    for (int p = 0; p < 4; ++p) {
      int idx = tid + p * 256;                 // 0..1023
      int row = idx >> 3, col8 = (idx & 7) * 8;
      uint4 v = *reinterpret_cast<const uint4*>(Ebd + (size_t)row * DD + k0 + col8);
      *reinterpret_cast<uint4*>(&Ea[row * 72 + col8]) = v;
    }
    // stage W tile [128][64]: fp32 global -> bf16 LDS
    #pragma unroll
    for (int p = 0; p < 8; ++p) {
      int idx = tid + p * 256;                 // 0..2047
      int row = idx >> 4, col4 = (idx & 15) * 4;
      float4 v = *reinterpret_cast<const float4*>(W + (size_t)(l0 + row) * DD + k0 + col4);
      ushort4 b4;
      b4.x = f2bf(v.x); b4.y = f2bf(v.y); b4.z = f2bf(v.z); b4.w = f2bf(v.w);
      *reinterpret_cast<ushort4*>(&Wb[row * 72 + col4]) = b4;
    }
    __syncthreads();
    #pragma unroll
    for (int ks = 0; ks < 64; ks += 32) {
      bf16x8 af[4], bfr[4];
      #pragma unroll
      for (int i = 0; i < 4; ++i)
        af[i] = *reinterpret_cast<const bf16x8*>(&Ea[(wm * 64 + i * 16 + c) * 72 + ks + q * 8]);
      #pragma unroll
      for (int j = 0; j < 4; ++j)
        bfr[j] = *reinterpret_cast<const bf16x8*>(&Wb[(wn * 64 + j * 16 + c) * 72 + ks + q * 8]);
      #pragma unroll
      for (int i = 0; i < 4; ++i)
        #pragma unroll
        for (int j = 0; j < 4; ++j)
          acc[i][j] = __builtin_amdgcn_mfma_f32_16x16x32_bf16(af[i], bfr[j], acc[i][j], 0, 0, 0);
    }
    __syncthreads();
  }

  // ---- epilogue: sigmoid -> P tile in LDS (aliases staging buffers)
  unsigned short* Pt = (unsigned short*)ldsbuf;   // [128][136] = 34816 B <= 36864
  #pragma unroll
  for (int i = 0; i < 4; ++i)
    #pragma unroll
    for (int j = 0; j < 4; ++j)
      #pragma unroll
      for (int r = 0; r < 4; ++r) {
        int b_loc = wm * 64 + i * 16 + q * 4 + r;
        int l_loc = wn * 64 + j * 16 + c;
        float z = acc[i][j][r];
        float pv = 1.0f / (1.0f + __expf(-z));
        Pt[b_loc * 136 + l_loc] = f2bf(pv);
      }
  __syncthreads();

  // ---- scatter: set p[row,col] = p_orig - 1 (idempotent under duplicates)
  float sval[2]; int sact[2], srow[2], scol[2];
  #pragma unroll
  for (int s = 0; s < 2; ++s) {
    int i = tid + s * 256;
    sact[s] = 0;
    int col = lcols[i], row = lrows[i];
    if (col >= l0 && col < l0 + 128) {
      sact[s] = 1; srow[s] = row & 127; scol[s] = col - l0;
      sval[s] = bf2f(Pt[srow[s] * 136 + scol[s]]);
    }
  }
  __syncthreads();
  #pragma unroll
  for (int s = 0; s < 2; ++s)
    if (sact[s]) Pt[srow[s] * 136 + scol[s]] = f2bf(sval[s] - 1.0f);
  __syncthreads();

  // ---- write P in [b][l] layout (contiguous 16B stores)
  #pragma unroll
  for (int p = 0; p < 8; ++p) {
    int idx = tid + p * 256;                  // 2048 chunks of 8
    int row = idx >> 4, col8 = (idx & 15) * 8;
    uint4 v = *reinterpret_cast<const uint4*>(&Pt[row * 136 + col8]);
    *reinterpret_cast<uint4*>(&Pbl[(size_t)row * LL + l0 + col8]) = v;
  }
  // ---- write P in [l][b] layout (LDS-transposed gather, 16B stores)
  #pragma unroll
  for (int p = 0; p < 8; ++p) {
    int idx = tid + p * 256;
    int lrow = idx >> 4, b8 = (idx & 15) * 8;
    __align__(16) unsigned short tmp[8];
    #pragma unroll
    for (int t = 0; t < 8; ++t) tmp[t] = Pt[(b8 + t) * 136 + lrow];
    *reinterpret_cast<uint4*>(&Plb[(size_t)(l0 + lrow) * BB + b8]) =
        *reinterpret_cast<const uint4*>(tmp);
  }
}

// ---------------------------------------------------------------------------
// K2: new_W = (1-lr*wd)*W - lr*(P^T @ E); grad_input += P @ W (split-K atomics).
// grid (6 d-slices of 128, 128 l-chunks of 1024). 32 iters of 32 W-rows each.
// ---------------------------------------------------------------------------
__global__ __launch_bounds__(256) void k2_update(const float* __restrict__ W,
                                                 const unsigned short* __restrict__ Edb,
                                                 const unsigned short* __restrict__ Pbl,
                                                 const unsigned short* __restrict__ Plb,
                                                 const float* __restrict__ lr_p,
                                                 float* __restrict__ grad,
                                                 float* __restrict__ newW) {
  __shared__ unsigned short Et[128 * 136];   // [d_loc][b]      34816 B
  __shared__ unsigned short Pb[128 * 40];    // [b][l_loc(32)]  10240 B
  __shared__ unsigned short Pl[32 * 136];    // [l_loc][b]       8704 B
  __shared__ unsigned short Wt[128 * 40];    // [d_loc][l_loc]  10240 B

  const int tid  = threadIdx.x;
  const int lane = tid & 63;
  const int wave = tid >> 6;
  const int wm = wave & 1, wn = wave >> 1;
  const int q = lane >> 4, c = lane & 15;
  const int ds0 = blockIdx.x * 128;
  const int l0  = blockIdx.y * 1024;
  const float lr = lr_p[0];
  const float decay = 1.0f - lr * WDC;

  // stage E^T slice once: Et[d_loc][b] from Edb[(ds0+d)*128 + b]
  #pragma unroll
  for (int p = 0; p < 8; ++p) {
    int idx = tid + p * 256;                  // 0..2047
    int row = idx >> 4, col8 = (idx & 15) * 8;
    *reinterpret_cast<uint4*>(&Et[row * 136 + col8]) =
        *reinterpret_cast<const uint4*>(&Edb[(size_t)(ds0 + row) * BB + col8]);
  }

  f32x4 gacc[4][4];
  #pragma unroll
  for (int i = 0; i < 4; ++i)
    #pragma unroll
    for (int j = 0; j < 4; ++j) gacc[i][j] = 0.0f;

  for (int it = 0; it < 32; ++it) {
    const int lt = l0 + it * 32;
    // stage P [b][l] tile: 128 rows x 32
    #pragma unroll
    for (int p = 0; p < 2; ++p) {
      int idx = tid + p * 256;                // 0..511
      int row = idx >> 2, col8 = (idx & 3) * 8;
      *reinterpret_cast<uint4*>(&Pb[row * 40 + col8]) =
          *reinterpret_cast<const uint4*>(&Pbl[(size_t)row * LL + lt + col8]);
    }
    // stage P [l][b] tile: 32 rows x 128
    #pragma unroll
    for (int p = 0; p < 2; ++p) {
      int idx = tid + p * 256;
      int row = idx >> 4, col8 = (idx & 15) * 8;
      *reinterpret_cast<uint4*>(&Pl[row * 136 + col8]) =
          *reinterpret_cast<const uint4*>(&Plb[(size_t)(lt + row) * BB + col8]);
    }
    // stage W tile 32(l) x 128(d) fp32 -> bf16 transposed [d][l]
    #pragma unroll
    for (int p = 0; p < 4; ++p) {
      int idx = tid + p * 256;                // 0..1023
      int row = idx >> 5, col4 = (idx & 31) * 4;
      float4 v = *reinterpret_cast<const float4*>(&W[(size_t)(lt + row) * DD + ds0 + col4]);
      Wt[(col4 + 0) * 40 + row] = f2bf(v.x);
      Wt[(col4 + 1) * 40 + row] = f2bf(v.y);
      Wt[(col4 + 2) * 40 + row] = f2bf(v.z);
      Wt[(col4 + 3) * 40 + row] = f2bf(v.w);
    }
    __syncthreads();

    // ---- wgrad GEMM: D[m=l(32)][n=d(128)], K=b(128). wave owns n-range wave*32.
    f32x4 wacc[2][2];
    #pragma unroll
    for (int i = 0; i < 2; ++i)
      #pragma unroll
      for (int j = 0; j < 2; ++j) wacc[i][j] = 0.0f;
    #pragma unroll
    for (int ks = 0; ks < 128; ks += 32) {
      bf16x8 a2[2], b2[2];
      #pragma unroll
      for (int i = 0; i < 2; ++i)
        a2[i] = *reinterpret_cast<const bf16x8*>(&Pl[(i * 16 + c) * 136 + ks + q * 8]);
      #pragma unroll
      for (int j = 0; j < 2; ++j)
        b2[j] = *reinterpret_cast<const bf16x8*>(&Et[(wave * 32 + j * 16 + c) * 136 + ks + q * 8]);
      #pragma unroll
      for (int i = 0; i < 2; ++i)
        #pragma unroll
        for (int j = 0; j < 2; ++j)
          wacc[i][j] = __builtin_amdgcn_mfma_f32_16x16x32_bf16(a2[i], b2[j], wacc[i][j], 0, 0, 0);
    }

    // ---- grad GEMM: D[m=b(128)][n=d(128)], K=l(32). waves 2x2.
    {
      bf16x8 ag[4], bg[4];
      #pragma unroll
      for (int i = 0; i < 4; ++i)
        ag[i] = *reinterpret_cast<const bf16x8*>(&Pb[(wm * 64 + i * 16 + c) * 40 + q * 8]);
      #pragma unroll
      for (int j = 0; j < 4; ++j)
        bg[j] = *reinterpret_cast<const bf16x8*>(&Wt[(wn * 64 + j * 16 + c) * 40 + q * 8]);
      #pragma unroll
      for (int i = 0; i < 4; ++i)
        #pragma unroll
        for (int j = 0; j < 4; ++j)
          gacc[i][j] = __builtin_amdgcn_mfma_f32_16x16x32_bf16(ag[i], bg[j], gacc[i][j], 0, 0, 0);
    }

    // ---- fused new_W store (W re-read is L2-hot: same tile staged above)
    #pragma unroll
    for (int i = 0; i < 2; ++i)
      #pragma unroll
      for (int j = 0; j < 2; ++j)
        #pragma unroll
        for (int r = 0; r < 4; ++r) {
          int lrow = i * 16 + q * 4 + r;              // 0..31
          int dcol = wave * 32 + j * 16 + c;          // 0..127
          size_t gaddr = (size_t)(lt + lrow) * DD + ds0 + dcol;
          float w = W[gaddr];
          newW[gaddr] = decay * w - lr * wacc[i][j][r];
        }
    __syncthreads();
  }

  // ---- grad_input split-K reduction via device-scope atomics
  #pragma unroll
  for (int i = 0; i < 4; ++i)
    #pragma unroll
    for (int j = 0; j < 4; ++j)
      #pragma unroll
      for (int r = 0; r < 4; ++r) {
        int brow = wm * 64 + i * 16 + q * 4 + r;
        int dcol = wn * 64 + j * 16 + c;
        atomicAdd(&grad[brow * DD + ds0 + dcol], gacc[i][j][r]);
      }
}

// ---------------------------------------------------------------------------
extern "C" void kernel_launch(void* const* d_in, const int* in_sizes, int n_in,
                              void* d_out, int out_size, void* d_ws, size_t ws_size,
                              hipStream_t stream) {
  const float* embed  = (const float*)d_in[0];   // 128*768
  const float* W      = (const float*)d_in[1];   // 131072*768
  const int*   labels = (const int*)d_in[2];     // 512*2 (int32 or int64, auto-detected)
  const float* lr_p   = (const float*)d_in[3];   // 1

  float* grad = (float*)d_out;                   // 98304
  float* newW = grad + (size_t)BB * DD;          // 131072*768

  unsigned short* Ebd = (unsigned short*)d_ws;            // E bf16 [b][d]
  unsigned short* Edb = Ebd + (size_t)BB * DD;            // E bf16 [d][b]
  unsigned short* Pbl = Edb + (size_t)BB * DD;            // P bf16 [b][l]
  unsigned short* Plb = Pbl + (size_t)BB * LL;            // P bf16 [l][b]
  // ws bytes needed: 2*(98304 + 98304 + 16777216 + 16777216) = 67,502,080

  k0_prep<<<384, 256, 0, stream>>>(embed, grad, Ebd, Edb);
  k1_logits<<<1024, 256, 0, stream>>>(W, Ebd, labels, Pbl, Plb);
  k2_update<<<dim3(6, 128), 256, 0, stream>>>(W, Edb, Pbl, Plb, lr_p, grad, newW);
}